// Round 2
// baseline (1102.552 us; speedup 1.0000x reference)
//
#include <hip/hip_runtime.h>

// Capsule dynamic routing, fully fused, fp32.
// x:[B,I,K]=32x2048x8, W:[J,I,D,K]=32x2048x16x8, out v:[B,J,D]=32x32x16.
// b-logits are linear in v (b_r = u_hat . sum_{r'<r} v_r'), so we only keep
// vsum[b,j,d]. Each routing iteration = pass kernel (recomputes u_hat from
// W,x; softmax over j in-wave; atomically accumulates s[b,j,d]) + tiny
// squash kernel (squash, vsum += v, re-zero s).
// R1 change: cross-block reduction via atomics into 64KB s-buffer instead of
// 16MB partials (squash was 3x61us latency-bound); NB 256->512 for 2 blk/CU.

#define BATCH 32
#define ICAP  2048
#define KDIM  8
#define JCAP  32
#define DDIM  16
#define JD    512            // JCAP*DDIM
#define S_ELEMS 16384        // BATCH*JCAP*DDIM
#define WROW  132            // LDS row stride (128 floats + pad 4, keeps 16B align)
#define EPSQ  1e-7f
#define NB    512            // i-chunk blocks per pass (2 blocks/CU)
#define ICHUNK (ICAP / NB)   // 4

// ---------------------------------------------------------------------------
// Pass kernel: grid = NB blocks (i-chunks), 512 threads = 8 waves.
// Wave w handles b in {w, w+8, w+16, w+24}. Lane l -> j = l&31, dhalf = l>>5.
// Per i: stage W[:,i,:,:] (4096 floats) in LDS, hoist lane's 64 floats to
// regs, then for each of 4 b: u[8] (8 MAC each), t = u.vsum (shfl over d),
// softmax over j (shfl butterfly), sacc += c*u. Epilogue: atomicAdd into s.
// ---------------------------------------------------------------------------
__global__ __launch_bounds__(512, 2)
void caps_pass(const float* __restrict__ W, const float* __restrict__ x,
               const float* __restrict__ vsum, float* __restrict__ s_out) {
    __shared__ float Wl[JCAP * WROW];          // 16.9 KB

    const int tid  = threadIdx.x;
    const int wave = tid >> 6;
    const int lane = tid & 63;
    const int j    = lane & 31;
    const int dh   = lane >> 5;                 // 0 or 1 (d half)
    const int i0   = blockIdx.x * ICHUNK;

    // cache vsum fragment + zero accumulators (4 b's per wave, 8 d's per lane)
    float vs[4][8];
    float sacc[4][8];
#pragma unroll
    for (int bb = 0; bb < 4; ++bb) {
        const int b = wave + 8 * bb;
        const float* vp = vsum + b * JD + j * DDIM + dh * 8;
        float4 a  = *reinterpret_cast<const float4*>(vp);
        float4 bq = *reinterpret_cast<const float4*>(vp + 4);
        vs[bb][0]=a.x; vs[bb][1]=a.y; vs[bb][2]=a.z; vs[bb][3]=a.w;
        vs[bb][4]=bq.x; vs[bb][5]=bq.y; vs[bb][6]=bq.z; vs[bb][7]=bq.w;
#pragma unroll
        for (int r = 0; r < 8; ++r) sacc[bb][r] = 0.f;
    }

    // W staging indices: float4 granularity. W[j,i,dk] -> f4 index
    // jj*65536 + i*32 + c  (row = 128 floats = 32 f4 chunks).
    const float4* Wv = reinterpret_cast<const float4*>(W);
    const int jj0 = tid >> 5, c0 = tid & 31;          // f4 #tid
    const int jj1 = (tid + 512) >> 5;                 // f4 #(tid+512), same c
    float4 pf0 = Wv[jj0 * 65536 + i0 * 32 + c0];
    float4 pf1 = Wv[jj1 * 65536 + i0 * 32 + c0];

    for (int ii = 0; ii < ICHUNK; ++ii) {
        const int i = i0 + ii;
        __syncthreads();                               // LDS free to overwrite
        *reinterpret_cast<float4*>(&Wl[jj0 * WROW + c0 * 4]) = pf0;
        *reinterpret_cast<float4*>(&Wl[jj1 * WROW + c0 * 4]) = pf1;
        __syncthreads();
        if (ii + 1 < ICHUNK) {                         // prefetch next i
            pf0 = Wv[jj0 * 65536 + (i + 1) * 32 + c0];
            pf1 = Wv[jj1 * 65536 + (i + 1) * 32 + c0];
        }

        // hoist this lane's W slice: dk = dh*64 + r*8 + k  (64 floats)
        float wreg[64];
        const float* wrow = &Wl[j * WROW + dh * 64];
#pragma unroll
        for (int r = 0; r < 8; ++r) {
            float4 a  = *reinterpret_cast<const float4*>(wrow + r * 8);
            float4 bq = *reinterpret_cast<const float4*>(wrow + r * 8 + 4);
            wreg[r*8+0]=a.x;  wreg[r*8+1]=a.y;  wreg[r*8+2]=a.z;  wreg[r*8+3]=a.w;
            wreg[r*8+4]=bq.x; wreg[r*8+5]=bq.y; wreg[r*8+6]=bq.z; wreg[r*8+7]=bq.w;
        }

#pragma unroll
        for (int bb = 0; bb < 4; ++bb) {
            const int b = wave + 8 * bb;
            const float* xp = x + (size_t)b * ICAP * KDIM + (size_t)i * KDIM;
            float4 xa = *reinterpret_cast<const float4*>(xp);
            float4 xb = *reinterpret_cast<const float4*>(xp + 4);
            const float xv[8] = {xa.x, xa.y, xa.z, xa.w, xb.x, xb.y, xb.z, xb.w};

            float u[8];
            float tpart = 0.f;
#pragma unroll
            for (int r = 0; r < 8; ++r) {
                float acc = 0.f;
#pragma unroll
                for (int k = 0; k < 8; ++k) acc = fmaf(wreg[r*8+k], xv[k], acc);
                u[r] = acc;
                tpart = fmaf(acc, vs[bb][r], tpart);
            }
            // full logit t[j]: combine the two d-halves (lane ^ 32)
            float t = tpart + __shfl_xor(tpart, 32);
            // softmax over j=32 (each j duplicated on lanes l and l^32)
            float m = t;
#pragma unroll
            for (int off = 1; off <= 16; off <<= 1)
                m = fmaxf(m, __shfl_xor(m, off));
            float e = __expf(t - m);
            float se = e;
#pragma unroll
            for (int off = 1; off <= 16; off <<= 1)
                se += __shfl_xor(se, off);
            const float c = e / se;
#pragma unroll
            for (int r = 0; r < 8; ++r) sacc[bb][r] = fmaf(c, u[r], sacc[bb][r]);
        }
    }

    // accumulate into global s[b,j,d] — each block owns disjoint partials,
    // cross-block sum via fire-and-forget atomics (resolved at L2).
#pragma unroll
    for (int bb = 0; bb < 4; ++bb) {
        const int b = wave + 8 * bb;
        float* p = s_out + b * JD + j * DDIM + dh * 8;
#pragma unroll
        for (int r = 0; r < 8; ++r) atomicAdd(p + r, sacc[bb][r]);
    }
}

// ---------------------------------------------------------------------------
// Squash s (16-lane butterfly over d), update vsum, re-zero s for next pass,
// optionally emit v to out. 64 KB total traffic — launch-latency bound.
// ---------------------------------------------------------------------------
__global__ __launch_bounds__(512)
void caps_squash(float* __restrict__ s, float* __restrict__ vsum,
                 float* __restrict__ out) {
    const int e = blockIdx.x * 512 + threadIdx.x;
    const float sv = s[e];
    float n2 = sv * sv;
#pragma unroll
    for (int off = 1; off <= 8; off <<= 1)
        n2 += __shfl_xor(n2, off);
    const float scale = n2 / ((1.f + n2) * sqrtf(n2 + EPSQ));
    const float v = sv * scale;
    vsum[e] += v;
    s[e] = 0.f;                      // ready for next pass
    if (out) out[e] = v;
}

extern "C" void kernel_launch(void* const* d_in, const int* in_sizes, int n_in,
                              void* d_out, int out_size, void* d_ws, size_t ws_size,
                              hipStream_t stream) {
    const float* x = (const float*)d_in[0];   // [32,2048,8]
    const float* W = (const float*)d_in[1];   // [32,2048,16,8]
    float* out = (float*)d_out;               // [32,32,16]

    float* vsum = (float*)d_ws;               // 64 KB
    float* s    = vsum + S_ELEMS;             // 64 KB

    hipMemsetAsync(vsum, 0, 2 * S_ELEMS * sizeof(float), stream);

    for (int r = 0; r < 3; ++r) {
        caps_pass<<<NB, 512, 0, stream>>>(W, x, vsum, s);
        caps_squash<<<S_ELEMS / 512, 512, 0, stream>>>(
            s, vsum, (r == 2) ? out : nullptr);
    }
}

// Round 3
// 185.014 us; speedup vs baseline: 5.9593x; 5.9593x over previous
//
#include <hip/hip_runtime.h>
#include <hip/hip_fp16.h>

// Capsule dynamic routing, fused, fp32 compute / fp16 block-partials.
// x:[B,I,K]=32x2048x8, W:[J,I,D,K]=32x2048x16x8, out v:[B,J,D]=32x32x16.
// b-logits are linear in v (b_r = u_hat . sum_{r'<r} v_r'): keep only
// vsum[b,j,d]. 3 passes of (recompute u_hat, softmax over j in-wave,
// accumulate s) + parallel reduce+squash.
// R3: no atomics (R2: 268MB HBM write-through, 512-way contention, 370us).
// fp16 partials (8MB fits proven ws in [8.45,16.8)MB; R1's NB auto-shrink
// to 128 left half the GPU idle). LDS chunk-column layout, 66-f4 stride:
// both staging writes and hoist reads touch each bank exactly 8x (b128
// minimum). 4 staging rounds of 2 i's with register prefetch.

#define BATCH 32
#define ICAP  2048
#define KDIM  8
#define JCAP  32
#define DDIM  16
#define JD    512            // JCAP*DDIM
#define S_ELEMS 16384        // BATCH*JCAP*DDIM
#define EPSQ  1e-7f

#define NB      256          // pass blocks (one 8-i chunk each)
#define ICH     8            // i's per block
#define ISTG    2            // i's per staging round
#define NROUND  (ICH / ISTG) // 4
#define COLF4   66           // f4 stride per 16B-chunk column (64 rows + 2 pad)
#define SLICEF4 (16 * COLF4) // 1056 f4 per i-slice
// LDS: ISTG * SLICEF4 f4 = 2112 * 16B = 33792 B

// ---------------------------------------------------------------------------
// Pass kernel: 256 blocks x 512 threads (8 waves). Wave w owns b in
// {w, w+8, w+16, w+24}; lane l -> j = l&31, dh = l>>5 (d half).
// Round: stage 2 i-slices of W to LDS (prefetched in regs), then for each i:
// hoist lane's 64 W floats (16x ds_read_b128, conflict-minimal), 4x
// (u = W.x, t = u.vsum, 32-wide softmax via shfl, sacc += c*u).
// Epilogue: fp16 partial slice per block (disjoint, no atomics).
// ---------------------------------------------------------------------------
__global__ __launch_bounds__(512, 2)
void caps_pass(const float* __restrict__ W, const float* __restrict__ x,
               const float* __restrict__ vsum, __half* __restrict__ partials) {
    __shared__ float4 Wl[ISTG * SLICEF4];

    const int tid  = threadIdx.x;
    const int wave = tid >> 6;
    const int lane = tid & 63;
    const int j    = lane & 31;
    const int dh   = lane >> 5;
    const int i0   = blockIdx.x * ICH;

    // vsum fragments + accumulators: 4 b's per wave, 8 d's per lane
    float vs[4][8], sacc[4][8];
#pragma unroll
    for (int bb = 0; bb < 4; ++bb) {
        const int b = wave + 8 * bb;
        const float* vp = vsum + b * JD + j * DDIM + dh * 8;
        float4 a  = *reinterpret_cast<const float4*>(vp);
        float4 bq = *reinterpret_cast<const float4*>(vp + 4);
        vs[bb][0]=a.x; vs[bb][1]=a.y; vs[bb][2]=a.z; vs[bb][3]=a.w;
        vs[bb][4]=bq.x; vs[bb][5]=bq.y; vs[bb][6]=bq.z; vs[bb][7]=bq.w;
#pragma unroll
        for (int r = 0; r < 8; ++r) sacc[bb][r] = 0.f;
    }

    // Staging decode: 4 f4 per thread per round. f = q*512 + tid:
    //   i_loc = f>>10, j_s = (f>>5)&31, c = f&31
    // global f4 idx = j_s*65536 + gi*32 + c   (W row = 128 floats = 32 f4)
    // LDS slot      = i_loc*SLICEF4 + (c&15)*COLF4 + 2*j_s + (c>>4)
    const float4* Wv = reinterpret_cast<const float4*>(W);
    int iloc_s[4], slot_s[4], gbase_s[4];
#pragma unroll
    for (int q = 0; q < 4; ++q) {
        const int f = q * 512 + tid;
        const int il = f >> 10, js = (f >> 5) & 31, c = f & 31;
        iloc_s[q]  = il;
        slot_s[q]  = il * SLICEF4 + (c & 15) * COLF4 + 2 * js + (c >> 4);
        gbase_s[q] = js * 65536 + c;               // + gi*32 at use
    }

    float4 pf[4];
#pragma unroll
    for (int q = 0; q < 4; ++q)
        pf[q] = Wv[gbase_s[q] + (i0 + iloc_s[q]) * 32];

    for (int rnd = 0; rnd < NROUND; ++rnd) {
        __syncthreads();                       // previous round done reading
#pragma unroll
        for (int q = 0; q < 4; ++q) Wl[slot_s[q]] = pf[q];
        __syncthreads();
        if (rnd + 1 < NROUND) {                // prefetch next round
            const int gi_n = i0 + (rnd + 1) * ISTG;
#pragma unroll
            for (int q = 0; q < 4; ++q)
                pf[q] = Wv[gbase_s[q] + (gi_n + iloc_s[q]) * 32];
        }

#pragma unroll
        for (int il = 0; il < ISTG; ++il) {
            const int gi = i0 + rnd * ISTG + il;

            // hoist lane's 64 W floats: w4[c'] = floats [dh*64 + 4c' ..+3]
            float4 w4[16];
            const int rbase = il * SLICEF4 + 2 * j + dh;
#pragma unroll
            for (int cp = 0; cp < 16; ++cp)
                w4[cp] = Wl[rbase + cp * COLF4];

#pragma unroll
            for (int bb = 0; bb < 4; ++bb) {
                const int b = wave + 8 * bb;
                const float* xp = x + ((size_t)b * ICAP + gi) * KDIM;
                const float4 x0 = *reinterpret_cast<const float4*>(xp);
                const float4 x1 = *reinterpret_cast<const float4*>(xp + 4);

                float u[8], tpart = 0.f;
#pragma unroll
                for (int r = 0; r < 8; ++r) {
                    const float4 wa = w4[2 * r], wb = w4[2 * r + 1];
                    float acc;
                    acc = wa.x * x0.x;
                    acc = fmaf(wa.y, x0.y, acc);
                    acc = fmaf(wa.z, x0.z, acc);
                    acc = fmaf(wa.w, x0.w, acc);
                    acc = fmaf(wb.x, x1.x, acc);
                    acc = fmaf(wb.y, x1.y, acc);
                    acc = fmaf(wb.z, x1.z, acc);
                    acc = fmaf(wb.w, x1.w, acc);
                    u[r] = acc;
                    tpart = fmaf(acc, vs[bb][r], tpart);
                }
                // full logit t[j] (combine d-halves), softmax over 32 j's
                float t = tpart + __shfl_xor(tpart, 32);
                float m = t;
#pragma unroll
                for (int off = 1; off <= 16; off <<= 1)
                    m = fmaxf(m, __shfl_xor(m, off));
                float e = __expf(t - m);
                float se = e;
#pragma unroll
                for (int off = 1; off <= 16; off <<= 1)
                    se += __shfl_xor(se, off);
                const float c = e / se;
#pragma unroll
                for (int r = 0; r < 8; ++r)
                    sacc[bb][r] = fmaf(c, u[r], sacc[bb][r]);
            }
        }
    }

    // fp16 partial slice, disjoint per block
    __half* pout = partials + (size_t)blockIdx.x * S_ELEMS;
#pragma unroll
    for (int bb = 0; bb < 4; ++bb) {
        const int b = wave + 8 * bb;
        union { int4 v; __half2 h[4]; } pk;
#pragma unroll
        for (int r = 0; r < 4; ++r)
            pk.h[r] = __floats2half2_rn(sacc[bb][2 * r], sacc[bb][2 * r + 1]);
        *reinterpret_cast<int4*>(pout + b * JD + j * DDIM + dh * 8) = pk.v;
    }
}

// ---------------------------------------------------------------------------
// Parallel reduce of 256 fp16 slices + squash. 256 blocks x 256 threads:
// wave sg sums slices [sg*64, sg*64+64) for 64 elements; LDS combine;
// wave 0 squashes (16-lane butterfly over d) and updates vsum.
// ---------------------------------------------------------------------------
__global__ __launch_bounds__(256)
void caps_reduce(const __half* __restrict__ partials, float* __restrict__ vsum,
                 float* __restrict__ out) {
    __shared__ float buf[4][80];
    const int tid = threadIdx.x;
    const int eL  = tid & 63;
    const int sg  = tid >> 6;
    const int e   = blockIdx.x * 64 + eL;

    float s = 0.f;
    const __half* p = partials + (size_t)(sg * 64) * S_ELEMS + e;
#pragma unroll 8
    for (int n = 0; n < 64; ++n)
        s += __half2float(p[(size_t)n * S_ELEMS]);
    buf[sg][eL] = s;
    __syncthreads();

    if (sg == 0) {
        s = buf[0][eL] + buf[1][eL] + buf[2][eL] + buf[3][eL];
        float n2 = s * s;
#pragma unroll
        for (int off = 1; off <= 8; off <<= 1)
            n2 += __shfl_xor(n2, off);
        const float scale = n2 / ((1.f + n2) * sqrtf(n2 + EPSQ));
        const float v = s * scale;
        vsum[e] += v;
        if (out) out[e] = v;
    }
}

extern "C" void kernel_launch(void* const* d_in, const int* in_sizes, int n_in,
                              void* d_out, int out_size, void* d_ws, size_t ws_size,
                              hipStream_t stream) {
    const float* x = (const float*)d_in[0];   // [32,2048,8]
    const float* W = (const float*)d_in[1];   // [32,2048,16,8]
    float* out = (float*)d_out;               // [32,32,16]

    float*  vsum     = (float*)d_ws;                       // 64 KB
    __half* partials = (__half*)((char*)d_ws + S_ELEMS * sizeof(float)); // 8 MB

    hipMemsetAsync(vsum, 0, S_ELEMS * sizeof(float), stream);

    for (int r = 0; r < 3; ++r) {
        caps_pass<<<NB, 512, 0, stream>>>(W, x, vsum, partials);
        caps_reduce<<<S_ELEMS / 64, 256, 0, stream>>>(
            partials, vsum, (r == 2) ? out : nullptr);
    }
}

// Round 4
// 176.261 us; speedup vs baseline: 6.2552x; 1.0497x over previous
//
#include <hip/hip_runtime.h>
#include <hip/hip_fp16.h>

// Capsule dynamic routing, fused, fp32 compute / fp16 block-partials.
// x:[B,I,K]=32x2048x8, W:[J,I,D,K]=32x2048x16x8, out v:[B,J,D]=32x32x16.
// b-logits are linear in v: keep only vsum[b,j,d]; 3 passes recompute u_hat.
// R4: force W register-residency. R2's VGPR=108 proved the compiler kept W
// in LDS and re-read it per b (4x ds_read_b128 traffic -> ~20us LDS pipe).
// Now W is pre-transposed ONCE into ws as Wt[i][chunk16B][2j+dh] so the pass
// reads each lane's 64 W floats via 16 coalesced global dwordx4 straight
// into VGPRs: no LDS, no barriers in the hot kernel. Softmax drops the max
// subtraction (|t|<~3, exp safe); divisions via v_rcp/v_rsq.

#define ICAP    2048
#define JD      512          // JCAP*DDIM
#define S_ELEMS 16384        // BATCH*JCAP*DDIM
#define EPSQ    1e-7f
#define NBP     256          // pass blocks
#define ICH     8            // i's per pass block

#if defined(__has_builtin) && __has_builtin(__builtin_amdgcn_rcpf)
#define FAST_RCP(x) __builtin_amdgcn_rcpf(x)
#else
#define FAST_RCP(x) (1.0f / (x))
#endif
#if defined(__has_builtin) && __has_builtin(__builtin_amdgcn_rsqf)
#define FAST_RSQ(x) __builtin_amdgcn_rsqf(x)
#else
#define FAST_RSQ(x) rsqrtf(x)
#endif

// ---------------------------------------------------------------------------
// One-time W transpose: W[j,i,dk] -> Wt f4-slot i*1024 + cc*64 + (2j+dh),
// holding floats W[j,i, dh*64 + 4cc .. +3]. Both global sides coalesced;
// LDS bounce with 66-f4 column stride keeps all LDS ops at the 8/bank b128
// minimum. 2048 blocks (one per i) x 256 threads.
// ---------------------------------------------------------------------------
__global__ __launch_bounds__(256)
void caps_transpose(const float4* __restrict__ Wv, float4* __restrict__ Wt) {
    __shared__ float4 buf[16 * 66];                   // 16.9 KB
    const int i = blockIdx.x;
    const int t = threadIdx.x;
#pragma unroll
    for (int q = 0; q < 4; ++q) {
        const int f = q * 256 + t;
        const int jj = f >> 5, c = f & 31;            // W row = 32 f4
        buf[(c & 15) * 66 + 2 * jj + (c >> 4)] =
            Wv[(size_t)jj * 65536 + (size_t)i * 32 + c];
    }
    __syncthreads();
    float4* dst = Wt + (size_t)i * 1024;
#pragma unroll
    for (int q = 0; q < 4; ++q) {
        const int o = q * 256 + t;
        dst[o] = buf[(o >> 6) * 66 + (o & 63)];
    }
}

// ---------------------------------------------------------------------------
// Pass kernel: 256 blocks x 512 threads (8 waves), no LDS. Wave w owns
// b in {w, w+8, w+16, w+24}; lane l -> j = l&31, dh = l>>5.
// Per i: 16 coalesced dwordx4 -> w4[16] regs (lane's 64 W floats), then 4x
// (u = W.x, t = u.vsum, combine d-halves, softmax over j in-wave, sacc+=c*u).
// Epilogue: fp16 partial slice per block (disjoint; reduce kernel sums).
// ---------------------------------------------------------------------------
__global__ __launch_bounds__(512, 1)
void caps_pass(const float4* __restrict__ Wt, const float* __restrict__ x,
               const float* __restrict__ vsum, __half* __restrict__ partials) {
    const int tid  = threadIdx.x;
    const int wave = tid >> 6;
    const int lane = tid & 63;
    const int j    = lane & 31;
    const int dh   = lane >> 5;
    const int i0   = blockIdx.x * ICH;

    float vs[4][8], sacc[4][8];
#pragma unroll
    for (int bb = 0; bb < 4; ++bb) {
        const int b = wave + 8 * bb;
        const float* vp = vsum + b * JD + j * 16 + dh * 8;
        float4 a  = *reinterpret_cast<const float4*>(vp);
        float4 bq = *reinterpret_cast<const float4*>(vp + 4);
        vs[bb][0]=a.x; vs[bb][1]=a.y; vs[bb][2]=a.z; vs[bb][3]=a.w;
        vs[bb][4]=bq.x; vs[bb][5]=bq.y; vs[bb][6]=bq.z; vs[bb][7]=bq.w;
#pragma unroll
        for (int r = 0; r < 8; ++r) sacc[bb][r] = 0.f;
    }

    const float4* wp = Wt + (size_t)i0 * 1024 + 2 * j + dh;

#pragma unroll 1
    for (int il = 0; il < ICH; ++il) {
        // lane's 64 W floats for this i: w4[cc] = W[j, i, dh*64+4cc .. +3]
        float4 w4[16];
#pragma unroll
        for (int cc = 0; cc < 16; ++cc)
            w4[cc] = wp[(size_t)il * 1024 + cc * 64];

        const int gi = i0 + il;
#pragma unroll
        for (int bb = 0; bb < 4; ++bb) {
            const int b = wave + 8 * bb;
            const float* xp = x + ((size_t)b * ICAP + gi) * 8;
            const float4 x0 = *reinterpret_cast<const float4*>(xp);
            const float4 x1 = *reinterpret_cast<const float4*>(xp + 4);

            float u[8], tpart = 0.f;
#pragma unroll
            for (int r = 0; r < 8; ++r) {
                const float4 wa = w4[2 * r], wb = w4[2 * r + 1];
                float acc;
                acc = wa.x * x0.x;
                acc = fmaf(wa.y, x0.y, acc);
                acc = fmaf(wa.z, x0.z, acc);
                acc = fmaf(wa.w, x0.w, acc);
                acc = fmaf(wb.x, x1.x, acc);
                acc = fmaf(wb.y, x1.y, acc);
                acc = fmaf(wb.z, x1.z, acc);
                acc = fmaf(wb.w, x1.w, acc);
                u[r] = acc;
                tpart = fmaf(acc, vs[bb][r], tpart);
            }
            // logit t[j] = combine d-halves; softmax over 32 j's, no max
            // subtraction (|t| <~ 3 by construction: u~N(0,0.28^2) dots
            // a vsum of norm <= 2).
            const float t = tpart + __shfl_xor(tpart, 32);
            const float e = __expf(t);
            float se = e;
#pragma unroll
            for (int off = 1; off <= 16; off <<= 1)
                se += __shfl_xor(se, off);
            const float c = e * FAST_RCP(se);
#pragma unroll
            for (int r = 0; r < 8; ++r)
                sacc[bb][r] = fmaf(c, u[r], sacc[bb][r]);
        }
    }

    // fp16 partial slice, disjoint per block
    __half* pout = partials + (size_t)blockIdx.x * S_ELEMS;
#pragma unroll
    for (int bb = 0; bb < 4; ++bb) {
        const int b = wave + 8 * bb;
        union { int4 v; __half2 h[4]; } pk;
#pragma unroll
        for (int r = 0; r < 4; ++r)
            pk.h[r] = __floats2half2_rn(sacc[bb][2 * r], sacc[bb][2 * r + 1]);
        *reinterpret_cast<int4*>(pout + b * JD + j * 16 + dh * 8) = pk.v;
    }
}

// ---------------------------------------------------------------------------
// Reduce 256 fp16 slices + squash. 256 blocks x 1024 threads: 16 waves,
// wave sg sums 16 slices (sg + 16n) for its 64 e's; LDS combine; wave 0
// squashes (butterfly over d=16) and updates vsum.
// ---------------------------------------------------------------------------
__global__ __launch_bounds__(1024)
void caps_reduce(const __half* __restrict__ partials, float* __restrict__ vsum,
                 float* __restrict__ out) {
    __shared__ float buf[16][80];
    const int tid = threadIdx.x;
    const int eL  = tid & 63;
    const int sg  = tid >> 6;
    const int e   = blockIdx.x * 64 + eL;

    float s = 0.f;
    const __half* p = partials + (size_t)sg * S_ELEMS + e;
#pragma unroll
    for (int n = 0; n < 16; ++n)
        s += __half2float(p[(size_t)(n * 16) * S_ELEMS]);
    buf[sg][eL] = s;
    __syncthreads();

    if (sg == 0) {
        s = 0.f;
#pragma unroll
        for (int k = 0; k < 16; ++k) s += buf[k][eL];
        float n2 = s * s;
#pragma unroll
        for (int off = 1; off <= 8; off <<= 1)
            n2 += __shfl_xor(n2, off);
        const float scale = n2 * FAST_RCP(1.f + n2) * FAST_RSQ(n2 + EPSQ);
        const float v = s * scale;
        vsum[e] += v;
        if (out) out[e] = v;
    }
}

extern "C" void kernel_launch(void* const* d_in, const int* in_sizes, int n_in,
                              void* d_out, int out_size, void* d_ws, size_t ws_size,
                              hipStream_t stream) {
    const float* x = (const float*)d_in[0];   // [32,2048,8]
    const float* W = (const float*)d_in[1];   // [32,2048,16,8]
    float* out = (float*)d_out;               // [32,32,16]

    // ws (256 MB proven): Wt 33.55 MB | vsum 64 KB | partials 8 MB
    float4* Wt       = (float4*)d_ws;
    float*  vsum     = (float*)((char*)d_ws + (size_t)ICAP * 1024 * 16);
    __half* partials = (__half*)((char*)vsum + S_ELEMS * sizeof(float));

    hipMemsetAsync(vsum, 0, S_ELEMS * sizeof(float), stream);
    caps_transpose<<<ICAP, 256, 0, stream>>>((const float4*)W, Wt);

    for (int r = 0; r < 3; ++r) {
        caps_pass<<<NBP, 512, 0, stream>>>(Wt, x, vsum, partials);
        caps_reduce<<<S_ELEMS / 64, 1024, 0, stream>>>(
            partials, vsum, (r == 2) ? out : nullptr);
    }
}

// Round 5
// 159.991 us; speedup vs baseline: 6.8913x; 1.1017x over previous
//
#include <hip/hip_runtime.h>
#include <hip/hip_fp16.h>

// Capsule dynamic routing, fused. fp32 accumulate, f16 W/x via v_dot2_f32_f16.
// x:[B,I,K]=32x2048x8, W:[J,I,D,K]=32x2048x16x8, out v:[B,J,D]=32x32x16.
// b-logits are linear in v: keep only vsum[b,j,d]; 3 passes recompute u_hat.
// R5: the fp32 u-math (64 MAC/(i,b,lane) x3 passes ~15us VALU floor) and
// fp32 W bytes were the budget. Wt stored as f16 (pass fetch halves), x
// pre-converted to f16, u via 32x fdot2 (2 MAC/instr, f32 acc). Pass 1 is
// templated FIRST=1: c==1/32 exactly, no vsum load, no softmax. memset node
// dropped (reduce writes vsum= on first). i-loop fully unrolled so the
// compiler pipelines W loads across i (R4's unroll-1 serialized them).

#define ICAP    2048
#define JD      512          // JCAP*DDIM
#define S_ELEMS 16384        // BATCH*JCAP*DDIM
#define EPSQ    1e-7f
#define NBP     256          // pass blocks (one 8-i chunk each)
#define ICH     8            // i's per pass block

typedef _Float16 h2v __attribute__((ext_vector_type(2)));
union H8 { int4 i4; h2v h[4]; };

#if defined(__has_builtin) && __has_builtin(__builtin_amdgcn_fdot2)
#define FDOT2(a, b, c) __builtin_amdgcn_fdot2((a), (b), (c), false)
#else
__device__ inline float FDOT2(h2v a, h2v b, float c) {
    return c + (float)a[0] * (float)b[0] + (float)a[1] * (float)b[1];
}
#endif
#if defined(__has_builtin) && __has_builtin(__builtin_amdgcn_rcpf)
#define FAST_RCP(x) __builtin_amdgcn_rcpf(x)
#else
#define FAST_RCP(x) (1.0f / (x))
#endif
#if defined(__has_builtin) && __has_builtin(__builtin_amdgcn_rsqf)
#define FAST_RSQ(x) __builtin_amdgcn_rsqf(x)
#else
#define FAST_RSQ(x) rsqrtf(x)
#endif

// ---------------------------------------------------------------------------
// One-time prep: W f32 -> Wt f16 in pass-coalesced layout, x f32 -> xh f16.
// Wt 16B-slot index: i*512 + cc*64 + (2j+dh), holding halves
// W[j, i, dh*64 + 8cc .. +7]. 2048 blocks (one per i) x 256 threads.
// ---------------------------------------------------------------------------
__global__ __launch_bounds__(256)
void caps_prep(const float4* __restrict__ Wv, const float* __restrict__ x,
               ushort4* __restrict__ Wt, __half* __restrict__ xh) {
    const int i = blockIdx.x;
    const int t = threadIdx.x;
#pragma unroll
    for (int q = 0; q < 4; ++q) {
        const int f  = q * 256 + t;
        const int jj = f >> 5, c = f & 31;          // W row = 32 x 16B
        const float4 w = Wv[(size_t)jj * 65536 + (size_t)i * 32 + c];
        ushort4 h;
        h.x = __half_as_ushort(__float2half(w.x));
        h.y = __half_as_ushort(__float2half(w.y));
        h.z = __half_as_ushort(__float2half(w.z));
        h.w = __half_as_ushort(__float2half(w.w));
        const int dh = c >> 4, cc = (c & 15) >> 1, sub = c & 1;
        Wt[((size_t)i * 512 + cc * 64 + 2 * jj + dh) * 2 + sub] = h;
    }
    // x: block i converts x[:, i, :] (32 b x 8 k = 256 elements)
    const int b = t >> 3, k = t & 7;
    const size_t xi = ((size_t)b * ICAP + i) * 8 + k;
    xh[xi] = __float2half(x[xi]);
}

// ---------------------------------------------------------------------------
// Pass kernel: 256 blocks x 512 threads (8 waves), no LDS. Wave w owns
// b in {w, w+8, w+16, w+24}; lane l -> j = l&31, dh = l>>5.
// Per i: 8 coalesced dwordx4 load lane's 64 W halves; per b: one dwordx4
// loads x halves, u via 32 fdot2, softmax over j in-wave (skipped when
// FIRST: c = 1/32 exactly), sacc += c*u. Epilogue: fp16 partials.
// ---------------------------------------------------------------------------
template <int FIRST>
__global__ __launch_bounds__(512, 1)
void caps_pass(const int4* __restrict__ Wt, const int4* __restrict__ xh,
               const float* __restrict__ vsum, __half* __restrict__ partials) {
    const int tid  = threadIdx.x;
    const int wave = tid >> 6;
    const int lane = tid & 63;
    const int j    = lane & 31;
    const int dh   = lane >> 5;
    const int i0   = blockIdx.x * ICH;

    float vs[4][8], sacc[4][8];
#pragma unroll
    for (int bb = 0; bb < 4; ++bb) {
        const int b = wave + 8 * bb;
        if (!FIRST) {
            const float* vp = vsum + b * JD + j * 16 + dh * 8;
            const float4 a  = *reinterpret_cast<const float4*>(vp);
            const float4 bq = *reinterpret_cast<const float4*>(vp + 4);
            vs[bb][0]=a.x; vs[bb][1]=a.y; vs[bb][2]=a.z; vs[bb][3]=a.w;
            vs[bb][4]=bq.x; vs[bb][5]=bq.y; vs[bb][6]=bq.z; vs[bb][7]=bq.w;
        }
#pragma unroll
        for (int r = 0; r < 8; ++r) sacc[bb][r] = 0.f;
    }

    const int4* wp = Wt + (size_t)i0 * 512 + 2 * j + dh;

#pragma unroll
    for (int il = 0; il < ICH; ++il) {
        H8 w8[8];
#pragma unroll
        for (int cc = 0; cc < 8; ++cc)
            w8[cc].i4 = wp[(size_t)il * 512 + cc * 64];

        const int gi = i0 + il;
#pragma unroll
        for (int bb = 0; bb < 4; ++bb) {
            const int b = wave + 8 * bb;
            H8 xv;
            xv.i4 = xh[(size_t)b * ICAP + gi];

            float u[8], tpart = 0.f;
#pragma unroll
            for (int r = 0; r < 8; ++r) {
                float acc = FDOT2(w8[r].h[0], xv.h[0], 0.f);
                acc = FDOT2(w8[r].h[1], xv.h[1], acc);
                acc = FDOT2(w8[r].h[2], xv.h[2], acc);
                acc = FDOT2(w8[r].h[3], xv.h[3], acc);
                u[r] = acc;
                if (!FIRST) tpart = fmaf(acc, vs[bb][r], tpart);
            }
            float c;
            if (FIRST) {
                c = 0.03125f;                        // softmax(0) over 32 j's
            } else {
                // logit t[j]: combine d-halves; softmax over 32 j's (no max
                // subtraction: |t| <~ 3 by construction).
                const float t = tpart + __shfl_xor(tpart, 32);
                const float e = __expf(t);
                float se = e;
#pragma unroll
                for (int off = 1; off <= 16; off <<= 1)
                    se += __shfl_xor(se, off);
                c = e * FAST_RCP(se);
            }
#pragma unroll
            for (int r = 0; r < 8; ++r)
                sacc[bb][r] = fmaf(c, u[r], sacc[bb][r]);
        }
    }

    // fp16 partial slice, disjoint per block
    __half* pout = partials + (size_t)blockIdx.x * S_ELEMS;
#pragma unroll
    for (int bb = 0; bb < 4; ++bb) {
        const int b = wave + 8 * bb;
        union { int4 v; __half2 h[4]; } pk;
#pragma unroll
        for (int r = 0; r < 4; ++r)
            pk.h[r] = __floats2half2_rn(sacc[bb][2 * r], sacc[bb][2 * r + 1]);
        *reinterpret_cast<int4*>(pout + b * JD + j * 16 + dh * 8) = pk.v;
    }
}

// ---------------------------------------------------------------------------
// Reduce 256 fp16 slices + squash. 256 blocks x 1024 threads: wave sg sums
// 16 slices for its 64 e's; LDS combine; wave 0 squashes (butterfly over
// d=16) and updates vsum (= on first pass: vsum never pre-zeroed).
// ---------------------------------------------------------------------------
__global__ __launch_bounds__(1024)
void caps_reduce(const __half* __restrict__ partials, float* __restrict__ vsum,
                 float* __restrict__ out, int first) {
    __shared__ float buf[16][80];
    const int tid = threadIdx.x;
    const int eL  = tid & 63;
    const int sg  = tid >> 6;
    const int e   = blockIdx.x * 64 + eL;

    float s = 0.f;
    const __half* p = partials + (size_t)sg * S_ELEMS + e;
#pragma unroll
    for (int n = 0; n < 16; ++n)
        s += __half2float(p[(size_t)(n * 16) * S_ELEMS]);
    buf[sg][eL] = s;
    __syncthreads();

    if (sg == 0) {
        s = 0.f;
#pragma unroll
        for (int k = 0; k < 16; ++k) s += buf[k][eL];
        float n2 = s * s;
#pragma unroll
        for (int off = 1; off <= 8; off <<= 1)
            n2 += __shfl_xor(n2, off);
        const float scale = n2 * FAST_RCP(1.f + n2) * FAST_RSQ(n2 + EPSQ);
        const float v = s * scale;
        const float old = first ? 0.f : vsum[e];     // vsum poisoned pre-r0
        vsum[e] = old + v;
        if (out) out[e] = v;
    }
}

extern "C" void kernel_launch(void* const* d_in, const int* in_sizes, int n_in,
                              void* d_out, int out_size, void* d_ws, size_t ws_size,
                              hipStream_t stream) {
    const float* x = (const float*)d_in[0];   // [32,2048,8]
    const float* W = (const float*)d_in[1];   // [32,2048,16,8]
    float* out = (float*)d_out;               // [32,32,16]

    // ws: Wt f16 16.78 MB | xh f16 1 MB | vsum 64 KB | partials fp16 8 MB
    ushort4* Wt      = (ushort4*)d_ws;
    __half*  xh      = (__half*)((char*)d_ws + (size_t)ICAP * 512 * 16);
    float*   vsum    = (float*)((char*)xh + (size_t)32 * ICAP * 8 * 2);
    __half*  partials= (__half*)((char*)vsum + S_ELEMS * sizeof(float));

    caps_prep<<<ICAP, 256, 0, stream>>>((const float4*)W, x, Wt, xh);

    caps_pass<1><<<NBP, 512, 0, stream>>>((const int4*)Wt, (const int4*)xh,
                                          vsum, partials);
    caps_reduce<<<S_ELEMS / 64, 1024, 0, stream>>>(partials, vsum, nullptr, 1);

    caps_pass<0><<<NBP, 512, 0, stream>>>((const int4*)Wt, (const int4*)xh,
                                          vsum, partials);
    caps_reduce<<<S_ELEMS / 64, 1024, 0, stream>>>(partials, vsum, nullptr, 0);

    caps_pass<0><<<NBP, 512, 0, stream>>>((const int4*)Wt, (const int4*)xh,
                                          vsum, partials);
    caps_reduce<<<S_ELEMS / 64, 1024, 0, stream>>>(partials, vsum, out, 0);
}